// Round 13
// baseline (24.966 us; speedup 1.0000x reference)
//
#include <hip/hip_runtime.h>

#define N 768
#define H 128
#define NM1 767
#define TI 48
#define TJ 48
#define LDSW (H + 4)   // pad -> row shift of 4 banks (proven conflict-free in R3/R12)

typedef __attribute__((ext_vector_type(8))) short bf16x8;
typedef __attribute__((ext_vector_type(4))) float f32x4;

// pack 8 fp32 -> 8 bf16 (RNE) via v_cvt_pk_bf16_f32 (guide T12 recipe)
static __device__ __forceinline__ bf16x8 cvt8(const float4 a, const float4 b) {
  int rx, ry, rz, rw;
  asm("v_cvt_pk_bf16_f32 %0, %1, %2" : "=v"(rx) : "v"(a.x), "v"(a.y));
  asm("v_cvt_pk_bf16_f32 %0, %1, %2" : "=v"(ry) : "v"(a.z), "v"(a.w));
  asm("v_cvt_pk_bf16_f32 %0, %1, %2" : "=v"(rz) : "v"(b.x), "v"(b.y));
  asm("v_cvt_pk_bf16_f32 %0, %1, %2" : "=v"(rw) : "v"(b.z), "v"(b.w));
  int4 r = {rx, ry, rz, rw};
  return __builtin_bit_cast(bf16x8, r);
}

__global__ __launch_bounds__(256) void fused_mfma(
    const float* __restrict__ z, const float* __restrict__ W1,
    const float* __restrict__ b1, const float* __restrict__ w2,
    const float* __restrict__ b2, float* __restrict__ out) {
  __shared__ __align__(16) float ush[TI * LDSW];
  __shared__ __align__(16) float vsh[TJ * LDSW];
  const int t = threadIdx.x;
  const int bi = (blockIdx.x >> 4) * TI;
  const int bj = (blockIdx.x & 15) * TJ;
  const int wv = t >> 6, lane = t & 63;
  const int lr = lane & 15;          // A row / B col within 16-tile
  const int lk8 = (lane >> 4) * 8;   // k-offset: our chosen bijection (shared by A & B)
  const int wn = wv * 32;            // wave's output-channel base (4 waves x 32 = 128)

  // ---- Phase A: U = z[bi..]@W1a^T -> ush ; Vb = z[bj..]@W1b^T + b1 -> vsh ----
  for (int half = 0; half < 2; ++half) {
    const int brow = half ? bj : bi;
    float* __restrict__ dst = half ? vsh : ush;
    f32x4 acc[3][2] = {};
#pragma unroll
    for (int kt = 0; kt < 4; ++kt) {           // K = 128 in 4 tiles of 32
      bf16x8 afr[3], bfr[2];
#pragma unroll
      for (int mt = 0; mt < 3; ++mt) {         // 48 rows = 3 m-tiles
        const float* p = z + (size_t)(brow + mt * 16 + lr) * H + kt * 32 + lk8;
        afr[mt] = cvt8(*(const float4*)p, *(const float4*)(p + 4));
      }
#pragma unroll
      for (int nt = 0; nt < 2; ++nt) {         // wave's 32 channels = 2 n-tiles
        const float* p = W1 + (size_t)(wn + nt * 16 + lr) * (2 * H) + half * H + kt * 32 + lk8;
        bfr[nt] = cvt8(*(const float4*)p, *(const float4*)(p + 4));
      }
#pragma unroll
      for (int mt = 0; mt < 3; ++mt)
#pragma unroll
        for (int nt = 0; nt < 2; ++nt)
          acc[mt][nt] = __builtin_amdgcn_mfma_f32_16x16x32_bf16(
              afr[mt], bfr[nt], acc[mt][nt], 0, 0, 0);
    }
    // C/D layout (HW-verified m89): col = lane&15, row = (lane>>4)*4 + reg
#pragma unroll
    for (int nt = 0; nt < 2; ++nt) {
      const int col = wn + nt * 16 + lr;
      const float bias = half ? b1[col] : 0.f;
#pragma unroll
      for (int mt = 0; mt < 3; ++mt) {
        const int rbase = mt * 16 + (lane >> 4) * 4;
#pragma unroll
        for (int r = 0; r < 4; ++r)
          dst[(rbase + r) * LDSW + col] = acc[mt][nt][r] + bias;
      }
    }
  }
  __syncthreads();

  // ---- Phase B: verbatim R12 (proven) ----
  const int tx = t & 15, ty = t >> 4;
  float acc[3][3] = {};
#pragma unroll 8
  for (int k = 0; k < H; k += 4) {
    const float4 w = *(const float4*)(w2 + k);  // uniform -> scalar load
    float4 uu[3], vv[3];
#pragma unroll
    for (int r = 0; r < 3; ++r) uu[r] = *(const float4*)&ush[(ty + 16 * r) * LDSW + k];
#pragma unroll
    for (int r = 0; r < 3; ++r) vv[r] = *(const float4*)&vsh[(tx + 16 * r) * LDSW + k];
#pragma unroll
    for (int a = 0; a < 3; ++a)
#pragma unroll
      for (int b = 0; b < 3; ++b) {
        acc[a][b] = fmaf(fmaxf(uu[a].x + vv[b].x, 0.f), w.x, acc[a][b]);
        acc[a][b] = fmaf(fmaxf(uu[a].y + vv[b].y, 0.f), w.y, acc[a][b]);
        acc[a][b] = fmaf(fmaxf(uu[a].z + vv[b].z, 0.f), w.z, acc[a][b]);
        acc[a][b] = fmaf(fmaxf(uu[a].w + vv[b].w, 0.f), w.w, acc[a][b]);
      }
  }
  const float bb = b2[0];
#pragma unroll
  for (int a = 0; a < 3; ++a) {
    const int i = bi + ty + 16 * a;
#pragma unroll
    for (int b = 0; b < 3; ++b) {
      const int j = bj + tx + 16 * b;
      if (i != j) out[(size_t)i * NM1 + j - (j > i ? 1 : 0)] = acc[a][b] + bb;
    }
  }
}

extern "C" void kernel_launch(void* const* d_in, const int* in_sizes, int n_in,
                              void* d_out, int out_size, void* d_ws, size_t ws_size,
                              hipStream_t stream) {
  const float* z  = (const float*)d_in[0];
  const float* W1 = (const float*)d_in[1];
  const float* b1 = (const float*)d_in[2];
  const float* W2 = (const float*)d_in[3];
  const float* b2 = (const float*)d_in[4];
  fused_mfma<<<256, 256, 0, stream>>>(z, W1, b1, W2, b2, (float*)d_out);
}